// Round 5
// baseline (4241.634 us; speedup 1.0000x reference)
//
#include <hip/hip_runtime.h>

// DGCNN forward, fp32 throughout.
// R5: kNN column sweep split 4-way across blocks (2048 blocks -> 4-5 resident/CU,
// was 512/2) + candidate merge kernel; BK=16 staging (LDS 43.5->30 KB);
// top-k LDS lists padded (stride 21/13) to kill 8-way bank conflicts.

#define NPTS   4096
#define NB     8
#define BNR    32768      // NB*NPTS
#define KNN    20
#define EPSBN  1e-5f
#define CAP    12         // per-row candidate buffer entries per merge round
#define NSPL   4          // column splits per row-block

__device__ __forceinline__ float lrelu(float x){ return x > 0.f ? x : 0.2f*x; }

__device__ __forceinline__ void topk_insert(float (&bv)[KNN], int (&bi)[KNN], float d, int mi){
#pragma unroll
  for (int j = 0; j < KNN; ++j){
    bool take = d > bv[j];
    float nv = take ? d : bv[j];
    int   ni = take ? mi : bi[j];
    float od = take ? bv[j] : d;
    int   oi = take ? bi[j] : mi;
    bv[j] = nv; bi[j] = ni; d = od; mi = oi;
  }
}

// x (8,6,4096) -> xt (8,4096,8), channels 6,7 zero-padded
__global__ __launch_bounds__(256) void k_transpose_pad(const float* __restrict__ x,
                                                       float* __restrict__ xt){
  int id = blockIdx.x*256 + threadIdx.x;          // 0..32767
  int b = id >> 12, n = id & (NPTS-1);
  const float* xb = x + (size_t)b*6*NPTS + n;
  float* o = xt + (size_t)id*8;
#pragma unroll
  for (int c = 0; c < 6; ++c) o[c] = xb[(size_t)c*NPTS];
  o[6] = 0.f; o[7] = 0.f;
}

// squared norm per row (c4 float4 groups, row stride xstride floats)
__global__ __launch_bounds__(256) void k_sqnorm(const float* __restrict__ X, int xstride, int c4,
                                                float* __restrict__ sq){
  int id = blockIdx.x*256 + threadIdx.x;
  const float4* r = (const float4*)(X + (size_t)id*xstride);
  float s = 0.f;
  for (int c = 0; c < c4; ++c){ float4 v = r[c]; s += v.x*v.x + v.y*v.y + v.z*v.z + v.w*v.w; }
  sq[id] = s;
}

// Fused kNN: block = 64 rows x 1024-col split of one batch. Distance tile in
// registers (4x8 micro, BK=16); per-row top-20 in LDS via threshold filter +
// candidate buffer + owner merge (pending-mask retry loop handles overflow).
// Emits per-split top-20 candidates; k_knn_merge combines the NSPL splits.
template<int K>
__global__ __launch_bounds__(256) void k_knn_fused(const float* __restrict__ X, int xstride,
                                                   const float* __restrict__ sqv,
                                                   float* __restrict__ cand_v,
                                                   int* __restrict__ cand_i){
  constexpr int BK   = (K < 16) ? K : 16;
  constexpr int COLS = NPTS / NSPL;
  __shared__ float As[BK][68];      // A k-subtile: [kk][row]
  __shared__ float Bs[BK][132];     // B k-subtile: [kk][col]
  __shared__ float sqs[128];
  __shared__ float thr[64];
  __shared__ float lv[64][21];
  __shared__ int   li[64][21];
  __shared__ int   cnt[64];
  __shared__ float cv[64][13];
  __shared__ int   ci[64][13];

  const int b  = blockIdx.z;
  const int i0 = blockIdx.x * 64;
  const int sp = blockIdx.y;
  const int c0 = sp * COLS;
  const int tid = threadIdx.x, tx = tid & 15, ty = tid >> 4;
  const float* Xb  = X + (size_t)b * NPTS * xstride;
  const float* sqb = sqv + b * NPTS;

  if (tid < 64){
    thr[tid] = -3e38f; cnt[tid] = 0;
#pragma unroll
    for (int j = 0; j < KNN; ++j){ lv[tid][j] = -3e38f; li[tid][j] = 0; }
  }
  float sqi[4];
#pragma unroll
  for (int r = 0; r < 4; ++r) sqi[r] = sqb[i0 + ty*4 + r];

  for (int j0 = c0; j0 < c0 + COLS; j0 += 128){
    float acc[4][8] = {};
    for (int k0 = 0; k0 < K; k0 += BK){
      // stage A: 64 rows x BK k  (row = tid&63, q = tid>>6 covers BK/4 k's)
      {
        int row = tid & 63, q = tid >> 6;
        const float* src = Xb + (size_t)(i0 + row)*xstride + k0;
#pragma unroll
        for (int k = q*(BK/4); k < (q+1)*(BK/4); ++k) As[k][row] = src[k];
      }
      // stage B: 128 cols x BK k  (col = tid&127, h = tid>>7 covers BK/2 k's)
      {
        int col = tid & 127, h = tid >> 7;
        const float* src = Xb + (size_t)(j0 + col)*xstride + k0;
#pragma unroll
        for (int k = h*(BK/2); k < (h+1)*(BK/2); ++k) Bs[k][col] = src[k];
      }
      if (k0 == 0 && tid < 128) sqs[tid] = sqb[j0 + tid];
      __syncthreads();
#pragma unroll
      for (int kk = 0; kk < BK; ++kk){
        float a[4], bb_[8];
        *(float4*)a        = *(const float4*)&As[kk][ty*4];
        *(float4*)&bb_[0]  = *(const float4*)&Bs[kk][tx*4];
        *(float4*)&bb_[4]  = *(const float4*)&Bs[kk][64 + tx*4];
#pragma unroll
        for (int r = 0; r < 4; ++r)
#pragma unroll
          for (int c = 0; c < 8; ++c)
            acc[r][c] = fmaf(a[r], bb_[c], acc[r][c]);
      }
      __syncthreads();
    }
    // candidate values: d = 2*acc - sq_i - sq_j (same fp order across rounds)
    float sq8[8];
#pragma unroll
    for (int c = 0; c < 4; ++c){ sq8[c] = sqs[tx*4 + c]; sq8[c+4] = sqs[64 + tx*4 + c]; }

    unsigned pending = 0xFFFFFFFFu;
    while (true){
      if (pending){
        float tr[4];
#pragma unroll
        for (int r = 0; r < 4; ++r) tr[r] = thr[ty*4 + r];
#pragma unroll
        for (int r = 0; r < 4; ++r)
#pragma unroll
          for (int c = 0; c < 8; ++c){
            unsigned bit = 1u << (r*8 + c);
            if (pending & bit){
              float val = 2.f*acc[r][c] - sqi[r] - sq8[c];
              if (val <= tr[r]) pending &= ~bit;
              else {
                int row = ty*4 + r;
                int pos = atomicAdd(&cnt[row], 1);
                if (pos < CAP){
                  int col = (c < 4) ? (j0 + tx*4 + c) : (j0 + 64 + tx*4 + c - 4);
                  cv[row][pos] = val; ci[row][pos] = col;
                  pending &= ~bit;
                }
              }
            }
          }
      }
      int any = __syncthreads_or(pending != 0u);
      if (tid < 64){
        int n = min(cnt[tid], CAP);
        for (int i2 = 0; i2 < n; ++i2){
          float val = cv[tid][i2]; int cc = ci[tid][i2];
          if (val > lv[tid][KNN-1]){
            int j = KNN-1;
            while (j > 0 && lv[tid][j-1] < val){
              lv[tid][j] = lv[tid][j-1]; li[tid][j] = li[tid][j-1]; --j;
            }
            lv[tid][j] = val; li[tid][j] = cc;
          }
        }
        thr[tid] = lv[tid][KNN-1];
        cnt[tid] = 0;
      }
      __syncthreads();
      if (!any) break;
    }
  }
  if (tid < 64){
    int gn = b*NPTS + i0 + tid;
#pragma unroll
    for (int j = 0; j < KNN; ++j){
      cand_v[(size_t)(sp*KNN + j)*BNR + gn] = lv[tid][j];
      cand_i[(size_t)(sp*KNN + j)*BNR + gn] = li[tid][j];
    }
  }
}

// merge NSPL per-split sorted top-20 lists -> final top-20 per row.
// splits processed ascending, strict > insert: lowest-index tie-break preserved.
__global__ __launch_bounds__(256) void k_knn_merge(const float* __restrict__ cand_v,
                                                   const int* __restrict__ cand_i,
                                                   int* __restrict__ idx){
  int gn = blockIdx.x*256 + threadIdx.x;
  float bv[KNN]; int bi[KNN];
#pragma unroll
  for (int j = 0; j < KNN; ++j){ bv[j] = -3e38f; bi[j] = -1; }
  for (int s = 0; s < NSPL; ++s){
#pragma unroll 1
    for (int t = 0; t < KNN; ++t){
      float d  = cand_v[(size_t)(s*KNN+t)*BNR + gn];
      int   mi = cand_i[(size_t)(s*KNN+t)*BNR + gn];
      if (d > bv[KNN-1]) topk_insert(bv, bi, d, mi);
    }
  }
#pragma unroll
  for (int j = 0; j < KNN; ++j) idx[(size_t)gn*KNN + j] = bi[j];
}

// PQ(M x 2*Och) = X(M x Kdim) @ [Wa; Wb]^T where Wa=W[:, :Kdim], Wb=W[:, Kdim:2Kdim].
// BM=128, BO=64, BK=16, 8x4 micro.
__global__ __launch_bounds__(256) void k_gemm_pq(const float* __restrict__ X, int xstride, int Kdim,
                                                 const float* __restrict__ W, int wstride, int Och,
                                                 float* __restrict__ PQ){
  __shared__ float Xs[16][132];
  __shared__ float Ws[16][68];
  const int m0 = blockIdx.x*128, o0 = blockIdx.y*64;
  const int tid = threadIdx.x, tx = tid & 15, ty = tid >> 4;
  const int O2 = 2*Och;
  float acc[8][4] = {};
  for (int k0 = 0; k0 < Kdim; k0 += 16){
#pragma unroll
    for (int i = 0; i < 8; ++i){
      int li = tid + 256*i;
      int row = li >> 4, kk = li & 15;
      bool ok = (k0 + kk) < Kdim;
      Xs[kk][row] = ok ? X[(size_t)(m0+row)*xstride + k0+kk] : 0.f;
    }
#pragma unroll
    for (int i = 0; i < 4; ++i){
      int li = tid + 256*i;
      int row = li >> 4, kk = li & 15;
      int orow = o0 + row;
      const float* wr = (orow < Och) ? (W + (size_t)orow*wstride)
                                     : (W + (size_t)(orow-Och)*wstride + Kdim);
      bool ok = (k0 + kk) < Kdim;
      Ws[kk][row] = ok ? wr[k0+kk] : 0.f;
    }
    __syncthreads();
#pragma unroll
    for (int kk = 0; kk < 16; ++kk){
      float xa[8], wb[4];
      *(float4*)&xa[0] = *(const float4*)&Xs[kk][ty*8];
      *(float4*)&xa[4] = *(const float4*)&Xs[kk][ty*8+4];
      *(float4*)wb     = *(const float4*)&Ws[kk][tx*4];
#pragma unroll
      for (int i = 0; i < 8; ++i)
#pragma unroll
        for (int j = 0; j < 4; ++j)
          acc[i][j] = fmaf(xa[i], wb[j], acc[i][j]);
    }
    __syncthreads();
  }
#pragma unroll
  for (int i = 0; i < 8; ++i){
    float4 v = make_float4(acc[i][0], acc[i][1], acc[i][2], acc[i][3]);
    *(float4*)&PQ[(size_t)(m0+ty*8+i)*O2 + o0 + tx*4] = v;
  }
}

// out[n,o] = lrelu(scale*(red_k P[mk,o] - P[n,o] + Q[n,o]) + beta); red=max if scale>=0 else min
// P(m,o) = PQ[m*2O + o]; Q(n,o) = PQ[n*2O + O + o]
__global__ __launch_bounds__(256) void k_gather_conv(const float* __restrict__ PQ,
                                                     const int* __restrict__ idx,
                                                     const float* __restrict__ g,
                                                     const float* __restrict__ bb,
                                                     const float* __restrict__ rm,
                                                     const float* __restrict__ rv,
                                                     float* __restrict__ Out, int oshift, int choff){
  const int O = 1 << oshift;
  int id = blockIdx.x*256 + threadIdx.x;
  int gn = id >> oshift;
  int o  = id & (O-1);
  int bbase = (gn >> 12) * NPTS;
  const int* ip = idx + (size_t)gn*KNN;
  float vmax = -3e38f, vmin = 3e38f;
#pragma unroll
  for (int k = 0; k < KNN; ++k){
    int m = ip[k];
    float v = PQ[((size_t)(bbase + m) << (oshift+1)) + o];
    vmax = fmaxf(vmax, v);
    vmin = fminf(vmin, v);
  }
  float scale = g[o] * rsqrtf(rv[o] + EPSBN);
  float beta  = bb[o] - rm[o]*scale;
  float R = (scale >= 0.f) ? vmax : vmin;
  size_t self = (size_t)gn << (oshift+1);
  float h = R - PQ[self + o] + PQ[self + O + o];
  Out[(size_t)gn*512 + choff + o] = lrelu(fmaf(scale, h, beta));
}

// h = lrelu(bn(xc @ W5^T)) tile (128x128, 8x8 micro, split col groups),
// fused partial max/sum over rows.
__global__ __launch_bounds__(256) void k_gemm_w5_pool(const float* __restrict__ X,
                                                      const float* __restrict__ W,
                                                      const float* __restrict__ g,
                                                      const float* __restrict__ bb,
                                                      const float* __restrict__ rm,
                                                      const float* __restrict__ rv,
                                                      float* __restrict__ pmax,
                                                      float* __restrict__ psum){
  __shared__ float Xs[16][132];
  __shared__ float Ws[16][132];
  __shared__ float red[2][16][128];
  const int m0 = blockIdx.x*128, o0 = blockIdx.y*128;
  const int tid = threadIdx.x, tx = tid & 15, ty = tid >> 4;
  float acc[8][8] = {};
  for (int k0 = 0; k0 < 512; k0 += 16){
#pragma unroll
    for (int i = 0; i < 8; ++i){
      int li = tid + 256*i;
      int row = li >> 4, kk = li & 15;
      Xs[kk][row] = X[(size_t)(m0+row)*512 + k0+kk];
      Ws[kk][row] = W[(size_t)(o0+row)*512 + k0+kk];
    }
    __syncthreads();
#pragma unroll
    for (int kk = 0; kk < 16; ++kk){
      float xa[8], wb[8];
      *(float4*)&xa[0] = *(const float4*)&Xs[kk][ty*8];
      *(float4*)&xa[4] = *(const float4*)&Xs[kk][ty*8+4];
      *(float4*)&wb[0] = *(const float4*)&Ws[kk][tx*4];
      *(float4*)&wb[4] = *(const float4*)&Ws[kk][64 + tx*4];
#pragma unroll
      for (int i = 0; i < 8; ++i)
#pragma unroll
        for (int j = 0; j < 8; ++j)
          acc[i][j] = fmaf(xa[i], wb[j], acc[i][j]);
    }
    __syncthreads();
  }
#pragma unroll
  for (int j = 0; j < 8; ++j){
    int ocol = (j < 4) ? (tx*4 + j) : (64 + tx*4 + j - 4);
    int o = o0 + ocol;
    float scale = g[o] * rsqrtf(rv[o] + EPSBN);
    float beta  = bb[o] - rm[o]*scale;
    float mx = -3e38f, sm = 0.f;
#pragma unroll
    for (int i = 0; i < 8; ++i){
      float h = lrelu(fmaf(scale, acc[i][j], beta));
      mx = fmaxf(mx, h);
      sm += h;
    }
    red[0][ty][ocol] = mx;
    red[1][ty][ocol] = sm;
  }
  __syncthreads();
  if (tid < 128){
    float mx = -3e38f, sm = 0.f;
#pragma unroll
    for (int t = 0; t < 16; ++t){
      mx = fmaxf(mx, red[0][t][tid]);
      sm += red[1][t][tid];
    }
    pmax[(size_t)blockIdx.x*1024 + o0 + tid] = mx;
    psum[(size_t)blockIdx.x*1024 + o0 + tid] = sm;
  }
}

__global__ __launch_bounds__(256) void k_pool_reduce(const float* __restrict__ pmax,
                                                     const float* __restrict__ psum,
                                                     float* __restrict__ pooled){
  int id = blockIdx.x*256 + threadIdx.x;   // 8192
  int b = id >> 10, o = id & 1023;
  float mx = -3e38f, sm = 0.f;
  for (int t = 0; t < 32; ++t){
    mx = fmaxf(mx, pmax[(size_t)(b*32+t)*1024 + o]);
    sm += psum[(size_t)(b*32+t)*1024 + o];
  }
  pooled[(size_t)b*2048 + o] = mx;
  pooled[(size_t)b*2048 + 1024 + o] = sm * (1.f/NPTS);
}

__global__ __launch_bounds__(256) void k_fc1(const float* __restrict__ pooled,
                                             const float* __restrict__ W,
                                             const float* __restrict__ g,
                                             const float* __restrict__ bb,
                                             const float* __restrict__ rm,
                                             const float* __restrict__ rv,
                                             float* __restrict__ out){
  __shared__ float4 xs[512];
  int b = blockIdx.x >> 1;
  int o = ((blockIdx.x & 1) << 8) + threadIdx.x;
  const float4* pr = (const float4*)(pooled + (size_t)b*2048);
  for (int l = threadIdx.x; l < 512; l += 256) xs[l] = pr[l];
  __syncthreads();
  const float4* wr = (const float4*)(W + (size_t)o*2048);
  float s0=0.f, s1=0.f, s2=0.f, s3=0.f;
#pragma unroll 4
  for (int c = 0; c < 512; ++c){
    float4 w = wr[c], v = xs[c];
    s0 = fmaf(v.x, w.x, s0); s1 = fmaf(v.y, w.y, s1);
    s2 = fmaf(v.z, w.z, s2); s3 = fmaf(v.w, w.w, s3);
  }
  float h = (s0+s1)+(s2+s3);
  float scale = g[o] * rsqrtf(rv[o] + EPSBN);
  float beta  = bb[o] - rm[o]*scale;
  out[(size_t)b*512 + o] = lrelu(fmaf(scale, h, beta));
}

__global__ __launch_bounds__(256) void k_fc2(const float* __restrict__ in,
                                             const float* __restrict__ W,
                                             const float* __restrict__ bias,
                                             const float* __restrict__ g,
                                             const float* __restrict__ bb,
                                             const float* __restrict__ rm,
                                             const float* __restrict__ rv,
                                             float* __restrict__ out){
  __shared__ float4 xs[128];
  int b = blockIdx.x;
  int o = threadIdx.x;
  const float4* pr = (const float4*)(in + (size_t)b*512);
  if (threadIdx.x < 128) xs[threadIdx.x] = pr[threadIdx.x];
  __syncthreads();
  const float4* wr = (const float4*)(W + (size_t)o*512);
  float s0=0.f, s1=0.f, s2=0.f, s3=0.f;
#pragma unroll 4
  for (int c = 0; c < 128; ++c){
    float4 w = wr[c], v = xs[c];
    s0 = fmaf(v.x, w.x, s0); s1 = fmaf(v.y, w.y, s1);
    s2 = fmaf(v.z, w.z, s2); s3 = fmaf(v.w, w.w, s3);
  }
  float h = (s0+s1)+(s2+s3) + bias[o];
  float scale = g[o] * rsqrtf(rv[o] + EPSBN);
  float beta  = bb[o] - rm[o]*scale;
  out[(size_t)b*256 + o] = lrelu(fmaf(scale, h, beta));
}

__global__ __launch_bounds__(64) void k_fc3(const float* __restrict__ in,
                                            const float* __restrict__ W,
                                            const float* __restrict__ bias,
                                            float* __restrict__ out){
  int t = threadIdx.x;
  if (t >= 16) return;
  int b = t >> 1, o = t & 1;
  const float* xr = in + (size_t)b*256;
  const float* wr = W + (size_t)o*256;
  float s = 0.f;
  for (int c = 0; c < 256; ++c) s = fmaf(xr[c], wr[c], s);
  out[b*2 + o] = s + bias[o];
}

extern "C" void kernel_launch(void* const* d_in, const int* in_sizes, int n_in,
                              void* d_out, int out_size, void* d_ws, size_t ws_size,
                              hipStream_t stream){
  (void)in_sizes; (void)n_in; (void)out_size;
  const float* x   = (const float*)d_in[0];
  const float* W1  = (const float*)d_in[1];
  const float* g1  = (const float*)d_in[2];
  const float* b1  = (const float*)d_in[3];
  const float* m1  = (const float*)d_in[4];
  const float* v1  = (const float*)d_in[5];
  const float* W2  = (const float*)d_in[6];
  const float* g2  = (const float*)d_in[7];
  const float* b2  = (const float*)d_in[8];
  const float* m2  = (const float*)d_in[9];
  const float* v2  = (const float*)d_in[10];
  const float* W3  = (const float*)d_in[11];
  const float* g3  = (const float*)d_in[12];
  const float* b3  = (const float*)d_in[13];
  const float* m3  = (const float*)d_in[14];
  const float* v3  = (const float*)d_in[15];
  const float* W4  = (const float*)d_in[16];
  const float* g4  = (const float*)d_in[17];
  const float* b4  = (const float*)d_in[18];
  const float* m4  = (const float*)d_in[19];
  const float* v4  = (const float*)d_in[20];
  const float* W5  = (const float*)d_in[21];
  const float* g5  = (const float*)d_in[22];
  const float* b5  = (const float*)d_in[23];
  const float* m5  = (const float*)d_in[24];
  const float* v5  = (const float*)d_in[25];
  const float* L1  = (const float*)d_in[26];
  const float* gl1 = (const float*)d_in[27];
  const float* bl1 = (const float*)d_in[28];
  const float* ml1 = (const float*)d_in[29];
  const float* vl1 = (const float*)d_in[30];
  const float* L2  = (const float*)d_in[31];
  const float* L2b = (const float*)d_in[32];
  const float* gl2 = (const float*)d_in[33];
  const float* bl2 = (const float*)d_in[34];
  const float* ml2 = (const float*)d_in[35];
  const float* vl2 = (const float*)d_in[36];
  const float* L3  = (const float*)d_in[37];
  const float* L3b = (const float*)d_in[38];

  // workspace layout (float offsets)
  float* ws    = (float*)d_ws;
  float* xt    = ws;                      //   262144
  float* sq    = ws + 262144;             //    32768
  int*   idx   = (int*)(ws + 294912);     //   655360 ints
  float* candv = ws + 950272;             //  2621440 (NSPL*20*BNR)
  int*   candi = (int*)(ws + 3571712);    //  2621440 ints
  float* PQ    = ws + 6193152;            // 16777216 (max: 32768 x 512)
  float* xc    = ws + 22970368;           // 16777216  (8,4096,512) concat x1..x4
  float* pmax  = ws + 39747584;           //   262144
  float* psum  = ws + 40009728;           //   262144
  float* pool  = ws + 40271872;           //    16384
  float* oA    = ws + 40288256;           //     4096
  float* oB    = ws + 40292352;           //     2048
  if (ws_size < (size_t)40294400 * 4) return;  // ~161 MB scratch

  k_transpose_pad<<<128, 256, 0, stream>>>(x, xt);

  // ---- edge conv 1: in xt (C=6 padded to 8), out xc[:,:,0:64] ----
  k_sqnorm<<<128, 256, 0, stream>>>(xt, 8, 2, sq);
  k_knn_fused<8><<<dim3(64,NSPL,8), 256, 0, stream>>>(xt, 8, sq, candv, candi);
  k_knn_merge<<<128, 256, 0, stream>>>(candv, candi, idx);
  k_gemm_pq<<<dim3(256,2), 256, 0, stream>>>(xt, 8, 6, W1, 12, 64, PQ);
  k_gather_conv<<<8192, 256, 0, stream>>>(PQ, idx, g1, b1, m1, v1, xc, 6, 0);

  // ---- edge conv 2: in xc[:,:,0:64], out xc[:,:,64:128] ----
  k_sqnorm<<<128, 256, 0, stream>>>(xc, 512, 16, sq);
  k_knn_fused<64><<<dim3(64,NSPL,8), 256, 0, stream>>>(xc, 512, sq, candv, candi);
  k_knn_merge<<<128, 256, 0, stream>>>(candv, candi, idx);
  k_gemm_pq<<<dim3(256,2), 256, 0, stream>>>(xc, 512, 64, W2, 128, 64, PQ);
  k_gather_conv<<<8192, 256, 0, stream>>>(PQ, idx, g2, b2, m2, v2, xc, 6, 64);

  // ---- edge conv 3: in xc[:,:,64:128], out xc[:,:,128:256] ----
  k_sqnorm<<<128, 256, 0, stream>>>(xc + 64, 512, 16, sq);
  k_knn_fused<64><<<dim3(64,NSPL,8), 256, 0, stream>>>(xc + 64, 512, sq, candv, candi);
  k_knn_merge<<<128, 256, 0, stream>>>(candv, candi, idx);
  k_gemm_pq<<<dim3(256,4), 256, 0, stream>>>(xc + 64, 512, 64, W3, 128, 128, PQ);
  k_gather_conv<<<16384, 256, 0, stream>>>(PQ, idx, g3, b3, m3, v3, xc, 7, 128);

  // ---- edge conv 4: in xc[:,:,128:256], out xc[:,:,256:512] ----
  k_sqnorm<<<128, 256, 0, stream>>>(xc + 128, 512, 32, sq);
  k_knn_fused<128><<<dim3(64,NSPL,8), 256, 0, stream>>>(xc + 128, 512, sq, candv, candi);
  k_knn_merge<<<128, 256, 0, stream>>>(candv, candi, idx);
  k_gemm_pq<<<dim3(256,8), 256, 0, stream>>>(xc + 128, 512, 128, W4, 256, 256, PQ);
  k_gather_conv<<<32768, 256, 0, stream>>>(PQ, idx, g4, b4, m4, v4, xc, 8, 256);

  // ---- global feature: h = lrelu(bn(xc @ W5^T)), max+mean pool over N ----
  k_gemm_w5_pool<<<dim3(256,8), 256, 0, stream>>>(xc, W5, g5, b5, m5, v5, pmax, psum);
  k_pool_reduce<<<32, 256, 0, stream>>>(pmax, psum, pool);

  // ---- classifier head ----
  k_fc1<<<16, 256, 0, stream>>>(pool, L1, gl1, bl1, ml1, vl1, oA);
  k_fc2<<<8, 256, 0, stream>>>(oA, L2, L2b, gl2, bl2, ml2, vl2, oB);
  k_fc3<<<1, 64, 0, stream>>>(oB, L3, L3b, (float*)d_out);
}